// Round 1
// baseline (95.142 us; speedup 1.0000x reference)
//
#include <hip/hip_runtime.h>
#include <hip/hip_bf16.h>

#define BLK 256
#define CAP 1024          // LDS staging capacity (elements) per array
#define NEG_HUGE -3.402823466e+38f

// ---------------------------------------------------------------------------
// Kernel 1: exclusive prefix sum of scope[] (S int32) -> offsets[] (S int32)
// Single block, 256 threads; each thread serially sums a chunk, thread 0
// scans the 256 partials, then each thread writes running offsets.
// ---------------------------------------------------------------------------
__global__ void scan_kernel(const int* __restrict__ scope,
                            int* __restrict__ offsets, int S) {
    __shared__ int partial[BLK];
    int tid = threadIdx.x;
    int chunk = (S + BLK - 1) / BLK;
    int begin = tid * chunk;
    int end   = begin + chunk; if (end > S) end = S;
    int s = 0;
    for (int i = begin; i < end; ++i) s += scope[i];
    partial[tid] = s;
    __syncthreads();
    if (tid == 0) {
        int run = 0;
        for (int i = 0; i < BLK; ++i) { int v = partial[i]; partial[i] = run; run += v; }
    }
    __syncthreads();
    int base = partial[tid];
    for (int i = begin; i < end; ++i) { offsets[i] = base; base += scope[i]; }
}

// ---------------------------------------------------------------------------
// Block-wide reduction (256 threads = 4 waves of 64). MAX or SUM.
// Returns the reduced value in ALL threads.
// ---------------------------------------------------------------------------
template <bool IS_MAX>
__device__ inline float block_reduce(float v) {
    __shared__ float sc[4];
    int lane = threadIdx.x & 63;
    int wave = threadIdx.x >> 6;
#pragma unroll
    for (int o = 32; o > 0; o >>= 1) {
        float other = __shfl_down(v, o, 64);
        v = IS_MAX ? fmaxf(v, other) : (v + other);
    }
    __syncthreads();                 // protect sc reuse across calls
    if (lane == 0) sc[wave] = v;
    __syncthreads();
    float r = sc[0];
#pragma unroll
    for (int w = 1; w < 4; ++w) r = IS_MAX ? fmaxf(r, sc[w]) : (r + sc[w]);
    return r;
}

// ---------------------------------------------------------------------------
// Kernel 2: one block per segment. Stage segment into LDS (if it fits),
// compute tmax/mmax, then tden/mden/A, then loss_seg = log(mden) - A/tden.
// ---------------------------------------------------------------------------
__global__ __launch_bounds__(BLK)
void seg_loss_kernel(const float* __restrict__ means,
                     const float* __restrict__ targets,
                     const int* __restrict__ offsets,
                     const int* __restrict__ scope,
                     float* __restrict__ seg_out, int S) {
    int seg = blockIdx.x;
    if (seg >= S) return;
    int start = offsets[seg];
    int len   = scope[seg];
    if (len <= 0) { if (threadIdx.x == 0) seg_out[seg] = 0.f; return; }

    __shared__ float sT[CAP];
    __shared__ float sM[CAP];
    bool staged = (len <= CAP);
    if (staged) {
        for (int i = threadIdx.x; i < len; i += BLK) {
            sT[i] = targets[start + i];
            sM[i] = means[start + i];
        }
        __syncthreads();
    }

    // pass 1: maxes
    float tmax = NEG_HUGE, mmax = NEG_HUGE;
    for (int i = threadIdx.x; i < len; i += BLK) {
        float t = staged ? sT[i] : targets[start + i];
        float m = staged ? sM[i] : means[start + i];
        tmax = fmaxf(tmax, t);
        mmax = fmaxf(mmax, m);
    }
    tmax = block_reduce<true>(tmax);
    mmax = block_reduce<true>(mmax);

    // pass 2: denominators + cross term
    float tden = 0.f, mden = 0.f, A = 0.f;
    for (int i = threadIdx.x; i < len; i += BLK) {
        float t = staged ? sT[i] : targets[start + i];
        float m = staged ? sM[i] : means[start + i];
        float et = __expf(t - tmax);
        float dm = m - mmax;
        tden += et;
        mden += __expf(dm);
        A    += et * dm;
    }
    tden = block_reduce<false>(tden);
    mden = block_reduce<false>(mden);
    A    = block_reduce<false>(A);

    if (threadIdx.x == 0) {
        // -sum(p*logq) = lse - A/tden   with lse = log(mden)
        seg_out[seg] = logf(mden) - A / tden;
    }
}

// ---------------------------------------------------------------------------
// Kernel 3: deterministic sum of S per-segment losses, divide by S.
// ---------------------------------------------------------------------------
__global__ __launch_bounds__(1024)
void reduce_kernel(const float* __restrict__ seg_loss,
                   float* __restrict__ out, int S) {
    __shared__ float wsum[16];
    int tid = threadIdx.x;
    float s = 0.f;
    for (int i = tid; i < S; i += 1024) s += seg_loss[i];
#pragma unroll
    for (int o = 32; o > 0; o >>= 1) s += __shfl_down(s, o, 64);
    int lane = tid & 63, wave = tid >> 6;
    if (lane == 0) wsum[wave] = s;
    __syncthreads();
    if (tid == 0) {
        float tot = 0.f;
#pragma unroll
        for (int w = 0; w < 16; ++w) tot += wsum[w];
        out[0] = tot / (float)S;
    }
}

extern "C" void kernel_launch(void* const* d_in, const int* in_sizes, int n_in,
                              void* d_out, int out_size, void* d_ws, size_t ws_size,
                              hipStream_t stream) {
    const float* means   = (const float*)d_in[0];
    const int*   scope   = (const int*)d_in[1];
    const float* targets = (const float*)d_in[2];
    int S = in_sizes[1];
    float* out = (float*)d_out;

    int*   offsets = (int*)d_ws;
    float* segl    = (float*)((char*)d_ws + (size_t)S * sizeof(int));

    scan_kernel<<<1, BLK, 0, stream>>>(scope, offsets, S);
    seg_loss_kernel<<<S, BLK, 0, stream>>>(means, targets, offsets, scope, segl, S);
    reduce_kernel<<<1, 1024, 0, stream>>>(segl, out, S);
}